// Round 4
// baseline (1070.035 us; speedup 1.0000x reference)
//
#include <hip/hip_runtime.h>
#include <hip/hip_bf16.h>
#include <math.h>

// Problem constants
static const int kN = 32768;   // tokens per batch

// NOTE: macro params must not be named x/y/z/w — the preprocessor substitutes
// them even after '.', so "(w).w" would expand to "(arg).arg".
#define FMA4(d, a, wv) { (d).x = fmaf((a), (wv).x, (d).x); (d).y = fmaf((a), (wv).y, (d).y); \
                         (d).z = fmaf((a), (wv).z, (d).z); (d).w = fmaf((a), (wv).w, (d).w); }

// ---------------------------------------------------------------------------
// K_zero: zero the split-K accumulators (d_ws is poisoned 0xAA pre-launch).
// 33792 floats = tok_acc (32768) + nrm_acc (1024), contiguous.
// ---------------------------------------------------------------------------
__global__ void k_zero(float* __restrict__ p, int n)
{
    int i = blockIdx.x * 256 + threadIdx.x;
    if (i < n) p[i] = 0.f;
}

// ---------------------------------------------------------------------------
// K0: fold Wx@Ws per head -> Wxs [256][256] (K-major), b_log = bx@Ws + bs
// ---------------------------------------------------------------------------
__global__ void k_wxs(const float* __restrict__ Wx, const float* __restrict__ Ws,
                      const float* __restrict__ bx, const float* __restrict__ bs,
                      float* __restrict__ Wxs, float* __restrict__ blog)
{
    __shared__ float ws_s[1024];           // Ws [32][32]
    int tid = threadIdx.x;
    for (int i = tid; i < 1024; i += 256) ws_s[i] = Ws[i];
    __syncthreads();
    int c = blockIdx.x;                    // 0..255 (K index)
    int h = tid >> 5, g = tid & 31;
    const float* wrow = &Wx[c * 256 + h * 32];
    float s = 0.f;
    #pragma unroll
    for (int d = 0; d < 32; d++) s += wrow[d] * ws_s[d * 32 + g];
    Wxs[c * 256 + tid] = s;
    if (c == 0) {
        float t = 0.f;
        #pragma unroll
        for (int d = 0; d < 32; d++) t += bx[h * 32 + d] * ws_s[d * 32 + g];
        blog[tid] = t + bs[g];
    }
}

// ---------------------------------------------------------------------------
// K1: LayerNorm over C=256. One wave per row, float4 per lane.
// ---------------------------------------------------------------------------
__global__ __launch_bounds__(256) void k_ln(const float* __restrict__ fx,
                                            const float* __restrict__ gam,
                                            const float* __restrict__ bet,
                                            float* __restrict__ out)
{
    int lane = threadIdx.x & 63;
    long row = (long)blockIdx.x * 4 + (threadIdx.x >> 6);
    float4 v = *(const float4*)&fx[row * 256 + lane * 4];
    float s  = v.x + v.y + v.z + v.w;
    float ss = v.x * v.x + v.y * v.y + v.z * v.z + v.w * v.w;
    for (int off = 32; off; off >>= 1) { s += __shfl_down(s, off); ss += __shfl_down(ss, off); }
    s = __shfl(s, 0); ss = __shfl(ss, 0);
    float mu = s * (1.f / 256.f);
    float rstd = rsqrtf(ss * (1.f / 256.f) - mu * mu + 1e-5f);
    float4 gv = *(const float4*)&gam[lane * 4];
    float4 bv = *(const float4*)&bet[lane * 4];
    float4 o;
    o.x = (v.x - mu) * rstd * gv.x + bv.x;
    o.y = (v.y - mu) * rstd * gv.y + bv.y;
    o.z = (v.z - mu) * rstd * gv.z + bv.z;
    o.w = (v.w - mu) * rstd * gv.w + bv.w;
    *(float4*)&out[row * 256 + lane * 4] = o;
}

// ---------------------------------------------------------------------------
// K2: GEMM [BN,256]x[256,256]. mode=blockIdx.y:
//   0: W=Wxs, +blog, /temp[h], per-head softmax -> slice_w
//   1: W=Wfx, +bfx                             -> fx_mid
// Tile 64 rows x 256 cols, KT=32, 256 thr, 8x8 micro (2x2 quadrants of 4x4).
// ---------------------------------------------------------------------------
__global__ __launch_bounds__(256) void k_gemm_mid(
    const float* __restrict__ A, const float* __restrict__ Wxs,
    const float* __restrict__ Wfx, const float* __restrict__ blog,
    const float* __restrict__ bfx, const float* __restrict__ temp,
    float* __restrict__ slice_w, float* __restrict__ fx_mid)
{
    const int mode = blockIdx.y;
    const float* __restrict__ W = mode ? Wfx : Wxs;
    const int tid = threadIdx.x;
    const int tx = tid & 31, ty = tid >> 5;
    const long row0 = (long)blockIdx.x * 64;

    __shared__ float sA[32][68];   // [k][row], padded, float4-aligned rows
    __shared__ float sW[32][256];  // [k][col]

    float4 acc[2][2][4];
    #pragma unroll
    for (int i = 0; i < 2; i++)
        #pragma unroll
        for (int j = 0; j < 2; j++)
            #pragma unroll
            for (int r = 0; r < 4; r++) acc[i][j][r] = make_float4(0.f, 0.f, 0.f, 0.f);

    for (int k0 = 0; k0 < 256; k0 += 32) {
        #pragma unroll
        for (int u = 0; u < 2; u++) {
            int q = tid * 2 + u;
            int r = q >> 3;
            int kc = (q & 7) * 4;
            float4 v = *(const float4*)&A[(row0 + r) * 256 + k0 + kc];
            sA[kc + 0][r] = v.x; sA[kc + 1][r] = v.y; sA[kc + 2][r] = v.z; sA[kc + 3][r] = v.w;
        }
        #pragma unroll
        for (int j = 0; j < 8; j++) {
            int q = tid + 256 * j;
            int kr = q >> 6;
            int col = (q & 63) * 4;
            *(float4*)&sW[kr][col] = *(const float4*)&W[(k0 + kr) * 256 + col];
        }
        __syncthreads();
        #pragma unroll
        for (int k = 0; k < 32; k++) {
            float4 a0 = *(const float4*)&sA[k][ty * 4];
            float4 a1 = *(const float4*)&sA[k][32 + ty * 4];
            float4 w0 = *(const float4*)&sW[k][tx * 4];
            float4 w1 = *(const float4*)&sW[k][128 + tx * 4];
            float ar0[4] = { a0.x, a0.y, a0.z, a0.w };
            float ar1[4] = { a1.x, a1.y, a1.z, a1.w };
            #pragma unroll
            for (int rr = 0; rr < 4; rr++) {
                FMA4(acc[0][0][rr], ar0[rr], w0);
                FMA4(acc[0][1][rr], ar0[rr], w1);
                FMA4(acc[1][0][rr], ar1[rr], w0);
                FMA4(acc[1][1][rr], ar1[rr], w1);
            }
        }
        __syncthreads();
    }

    if (mode == 0) {
        #pragma unroll
        for (int j = 0; j < 2; j++) {
            int col = j * 128 + tx * 4;
            int h = col >> 5;
            float rt = 1.0f / temp[h];
            float4 bl = *(const float4*)&blog[col];
            #pragma unroll
            for (int i = 0; i < 2; i++)
                #pragma unroll
                for (int rr = 0; rr < 4; rr++) {
                    float4 z;
                    z.x = (acc[i][j][rr].x + bl.x) * rt;
                    z.y = (acc[i][j][rr].y + bl.y) * rt;
                    z.z = (acc[i][j][rr].z + bl.z) * rt;
                    z.w = (acc[i][j][rr].w + bl.w) * rt;
                    float m = fmaxf(fmaxf(z.x, z.y), fmaxf(z.z, z.w));
                    m = fmaxf(m, __shfl_xor(m, 1));
                    m = fmaxf(m, __shfl_xor(m, 2));
                    m = fmaxf(m, __shfl_xor(m, 4));
                    float4 e;
                    e.x = expf(z.x - m); e.y = expf(z.y - m);
                    e.z = expf(z.z - m); e.w = expf(z.w - m);
                    float s = e.x + e.y + e.z + e.w;
                    s += __shfl_xor(s, 1);
                    s += __shfl_xor(s, 2);
                    s += __shfl_xor(s, 4);
                    float inv = 1.0f / s;
                    e.x *= inv; e.y *= inv; e.z *= inv; e.w *= inv;
                    long row = row0 + i * 32 + ty * 4 + rr;
                    *(float4*)&slice_w[row * 256 + col] = e;
                }
        }
    } else {
        #pragma unroll
        for (int j = 0; j < 2; j++) {
            int col = j * 128 + tx * 4;
            float4 bl = *(const float4*)&bfx[col];
            #pragma unroll
            for (int i = 0; i < 2; i++)
                #pragma unroll
                for (int rr = 0; rr < 4; rr++) {
                    float4 o;
                    o.x = acc[i][j][rr].x + bl.x;
                    o.y = acc[i][j][rr].y + bl.y;
                    o.z = acc[i][j][rr].z + bl.z;
                    o.w = acc[i][j][rr].w + bl.w;
                    long row = row0 + i * 32 + ty * 4 + rr;
                    *(float4*)&fx_mid[row * 256 + col] = o;
                }
        }
    }
}

// ---------------------------------------------------------------------------
// K3: slice_token/slice_norm reduction over N (split-K + atomics).
// grid (16 chunks, 32 bh), 256 thr. Thread owns (g, d0..d0+3).
// ---------------------------------------------------------------------------
__global__ __launch_bounds__(256) void k_reduce(
    const float* __restrict__ slice_w, const float* __restrict__ fx_mid,
    float* __restrict__ tok_acc, float* __restrict__ nrm_acc)
{
    const int bh = blockIdx.y;
    const int b = bh >> 3, h = bh & 7;
    const int tid = threadIdx.x;
    const int g = tid >> 3, dq = tid & 7, d0 = dq * 4;
    __shared__ float sw_t[32][36];
    __shared__ float fm_t[32][36];
    float4 acc = make_float4(0.f, 0.f, 0.f, 0.f);
    float nacc = 0.f;
    long base = (long)b * kN + (long)blockIdx.x * 2048;

    for (int t0 = 0; t0 < 2048; t0 += 32) {
        int r = tid >> 3, q = tid & 7;
        long gaddr = (base + t0 + r) * 256 + h * 32 + q * 4;
        *(float4*)&sw_t[r][q * 4] = *(const float4*)&slice_w[gaddr];
        *(float4*)&fm_t[r][q * 4] = *(const float4*)&fx_mid[gaddr];
        __syncthreads();
        #pragma unroll 8
        for (int rr = 0; rr < 32; rr++) {
            float w = sw_t[rr][g];
            float4 f = *(const float4*)&fm_t[rr][d0];
            acc.x += w * f.x; acc.y += w * f.y; acc.z += w * f.z; acc.w += w * f.w;
            if (dq == 0) nacc += w;
        }
        __syncthreads();
    }
    float* ta = &tok_acc[(bh * 32 + g) * 32 + d0];
    atomicAdd(&ta[0], acc.x); atomicAdd(&ta[1], acc.y);
    atomicAdd(&ta[2], acc.z); atomicAdd(&ta[3], acc.w);
    if (dq == 0) atomicAdd(&nrm_acc[bh * 32 + g], nacc);
}

// ---------------------------------------------------------------------------
// K4: per-(b,h) token block: normalize, attn(G=32), LN, MLP, fold with Wo.
// 32 blocks x 256 thr. Thread owns (g = tid/8, d0 = (tid%8)*4).
// ~52KB LDS (Wo read through L2 directly — it's only 256KB total).
// ---------------------------------------------------------------------------
__global__ __launch_bounds__(256) void k_tokens(
    const float* __restrict__ tok_acc, const float* __restrict__ nrm_acc,
    const float* __restrict__ Wq, const float* __restrict__ Wk, const float* __restrict__ Wv,
    const float* __restrict__ tlng, const float* __restrict__ tlnb,
    const float* __restrict__ W1, const float* __restrict__ b1,
    const float* __restrict__ W2, const float* __restrict__ b2,
    const float* __restrict__ Wo, float* __restrict__ tokensWo)
{
    const int bh = blockIdx.x, h = bh & 7;
    const int tid = threadIdx.x;
    const int g = tid >> 3, dq = tid & 7, d0 = dq * 4;
    __shared__ float t[32][32], qm[32][32], km[32][32], vm[32][32];
    __shared__ float att[32][33], ot[32][32], hn[32][32], tk[32][32];
    __shared__ float h1[32][128];
    __shared__ float mu_s[32], rs_s[32];

    {
        float inv = 1.0f / (nrm_acc[bh * 32 + g] + 1e-5f);
        #pragma unroll
        for (int u = 0; u < 4; u++)
            t[g][d0 + u] = tok_acc[(bh * 32 + g) * 32 + d0 + u] * inv;
    }
    __syncthreads();
    #pragma unroll
    for (int u = 0; u < 4; u++) {
        int d = d0 + u;
        float sq = 0.f, sk = 0.f, sv = 0.f;
        for (int dd = 0; dd < 32; dd++) {
            float tv = t[g][dd];
            sq = fmaf(tv, Wq[dd * 32 + d], sq);
            sk = fmaf(tv, Wk[dd * 32 + d], sk);
            sv = fmaf(tv, Wv[dd * 32 + d], sv);
        }
        qm[g][d] = sq; km[g][d] = sk; vm[g][d] = sv;
    }
    __syncthreads();
    const float SC = 0.17677669529663687f;   // 32^-0.5
    #pragma unroll
    for (int u = 0; u < 4; u++) {
        int gk = d0 + u;
        float s = 0.f;
        for (int dd = 0; dd < 32; dd++) s = fmaf(qm[g][dd], km[gk][dd], s);
        att[g][gk] = s * SC;
    }
    __syncthreads();
    if (tid < 32) {
        float m = -1e30f;
        for (int j = 0; j < 32; j++) m = fmaxf(m, att[tid][j]);
        float s = 0.f;
        for (int j = 0; j < 32; j++) { float e = expf(att[tid][j] - m); att[tid][j] = e; s += e; }
        float inv = 1.0f / s;
        for (int j = 0; j < 32; j++) att[tid][j] *= inv;
    }
    __syncthreads();
    #pragma unroll
    for (int u = 0; u < 4; u++) {
        int d = d0 + u;
        float s = 0.f;
        for (int kk = 0; kk < 32; kk++) s = fmaf(att[g][kk], vm[kk][d], s);
        ot[g][d] = s + t[g][d];
    }
    __syncthreads();
    if (tid < 32) {
        float s = 0.f, ss = 0.f;
        for (int dd = 0; dd < 32; dd++) { float v = ot[tid][dd]; s += v; ss += v * v; }
        float mu = s * (1.f / 32.f);
        mu_s[tid] = mu;
        rs_s[tid] = rsqrtf(ss * (1.f / 32.f) - mu * mu + 1e-5f);
    }
    __syncthreads();
    #pragma unroll
    for (int u = 0; u < 4; u++) {
        int d = d0 + u;
        hn[g][d] = (ot[g][d] - mu_s[g]) * rs_s[g] * tlng[d] + tlnb[d];
    }
    __syncthreads();
    for (int c = dq * 16; c < dq * 16 + 16; c++) {
        float s = b1[c];
        for (int dd = 0; dd < 32; dd++) s = fmaf(hn[g][dd], W1[dd * 128 + c], s);
        h1[g][c] = 0.5f * s * (1.0f + erff(s * 0.70710678118654752f));
    }
    __syncthreads();
    #pragma unroll
    for (int u = 0; u < 4; u++) {
        int d = d0 + u;
        float s = b2[d];
        for (int c = 0; c < 128; c++) s = fmaf(h1[g][c], W2[c * 32 + d], s);
        tk[g][d] = s + ot[g][d];
    }
    __syncthreads();
    {
        int c0 = dq * 32;
        for (int c = c0; c < c0 + 32; c++) {
            float s = 0.f;
            for (int dd = 0; dd < 32; dd++) s = fmaf(tk[g][dd], Wo[(h * 32 + dd) * 256 + c], s);
            tokensWo[(bh * 32 + g) * 256 + c] = s;
        }
    }
}

// ---------------------------------------------------------------------------
// K5: out = slice_w @ tokensWo[b] + bo + fx_norm. Same tiling as K2.
// ---------------------------------------------------------------------------
__global__ __launch_bounds__(256) void k_gemm_out(
    const float* __restrict__ A, const float* __restrict__ tokensWo,
    const float* __restrict__ bo, const float* __restrict__ fx_norm,
    float* __restrict__ out)
{
    const int tid = threadIdx.x;
    const int tx = tid & 31, ty = tid >> 5;
    const long row0 = (long)blockIdx.x * 64;
    const int b = (int)(row0 >> 15);
    const float* __restrict__ W = tokensWo + (size_t)b * 65536;

    __shared__ float sA[32][68];
    __shared__ float sW[32][256];

    float4 acc[2][2][4];
    #pragma unroll
    for (int i = 0; i < 2; i++)
        #pragma unroll
        for (int j = 0; j < 2; j++)
            #pragma unroll
            for (int r = 0; r < 4; r++) acc[i][j][r] = make_float4(0.f, 0.f, 0.f, 0.f);

    for (int k0 = 0; k0 < 256; k0 += 32) {
        #pragma unroll
        for (int u = 0; u < 2; u++) {
            int q = tid * 2 + u;
            int r = q >> 3;
            int kc = (q & 7) * 4;
            float4 v = *(const float4*)&A[(row0 + r) * 256 + k0 + kc];
            sA[kc + 0][r] = v.x; sA[kc + 1][r] = v.y; sA[kc + 2][r] = v.z; sA[kc + 3][r] = v.w;
        }
        #pragma unroll
        for (int j = 0; j < 8; j++) {
            int q = tid + 256 * j;
            int kr = q >> 6;
            int col = (q & 63) * 4;
            *(float4*)&sW[kr][col] = *(const float4*)&W[(k0 + kr) * 256 + col];
        }
        __syncthreads();
        #pragma unroll
        for (int k = 0; k < 32; k++) {
            float4 a0 = *(const float4*)&sA[k][ty * 4];
            float4 a1 = *(const float4*)&sA[k][32 + ty * 4];
            float4 w0 = *(const float4*)&sW[k][tx * 4];
            float4 w1 = *(const float4*)&sW[k][128 + tx * 4];
            float ar0[4] = { a0.x, a0.y, a0.z, a0.w };
            float ar1[4] = { a1.x, a1.y, a1.z, a1.w };
            #pragma unroll
            for (int rr = 0; rr < 4; rr++) {
                FMA4(acc[0][0][rr], ar0[rr], w0);
                FMA4(acc[0][1][rr], ar0[rr], w1);
                FMA4(acc[1][0][rr], ar1[rr], w0);
                FMA4(acc[1][1][rr], ar1[rr], w1);
            }
        }
        __syncthreads();
    }

    #pragma unroll
    for (int j = 0; j < 2; j++) {
        int col = j * 128 + tx * 4;
        float4 bl = *(const float4*)&bo[col];
        #pragma unroll
        for (int i = 0; i < 2; i++)
            #pragma unroll
            for (int rr = 0; rr < 4; rr++) {
                long row = row0 + i * 32 + ty * 4 + rr;
                float4 fn = *(const float4*)&fx_norm[row * 256 + col];
                float4 o;
                o.x = acc[i][j][rr].x + bl.x + fn.x;
                o.y = acc[i][j][rr].y + bl.y + fn.y;
                o.z = acc[i][j][rr].z + bl.z + fn.z;
                o.w = acc[i][j][rr].w + bl.w + fn.w;
                *(float4*)&out[row * 256 + col] = o;
            }
    }
}

// ---------------------------------------------------------------------------
extern "C" void kernel_launch(void* const* d_in, const int* in_sizes, int n_in,
                              void* d_out, int out_size, void* d_ws, size_t ws_size,
                              hipStream_t stream)
{
    const float* fx   = (const float*)d_in[0];
    const float* ln_g = (const float*)d_in[1];
    const float* ln_b = (const float*)d_in[2];
    const float* Wx   = (const float*)d_in[3];
    const float* bx   = (const float*)d_in[4];
    const float* Wfx  = (const float*)d_in[5];
    const float* bfx  = (const float*)d_in[6];
    const float* Ws   = (const float*)d_in[7];
    const float* bs   = (const float*)d_in[8];
    const float* temp = (const float*)d_in[9];
    const float* Wq   = (const float*)d_in[10];
    const float* Wk   = (const float*)d_in[11];
    const float* Wv   = (const float*)d_in[12];
    const float* tlng = (const float*)d_in[13];
    const float* tlnb = (const float*)d_in[14];
    const float* W1   = (const float*)d_in[15];
    const float* b1   = (const float*)d_in[16];
    const float* W2   = (const float*)d_in[17];
    const float* b2   = (const float*)d_in[18];
    const float* Wo   = (const float*)d_in[19];
    const float* bo   = (const float*)d_in[20];
    float* out = (float*)d_out;

    char* ws = (char*)d_ws;
    float* fx_norm = (float*)(ws + 0);            // 134217728 B
    float* slice_w = (float*)(ws + 134217728);    // 134217728 B
    float* fx_mid  = (float*)(ws + 268435456);    // 134217728 B
    float* Wxs     = (float*)(ws + 402653184);    // 262144 B
    float* blog    = (float*)(ws + 402915328);    // 1024 B
    float* tok_acc = (float*)(ws + 402916352);    // 131072 B
    float* nrm_acc = (float*)(ws + 403047424);    // 4096 B
    float* tokWo   = (float*)(ws + 403051520);    // 1048576 B
    if (ws_size < 404100096ULL) return;           // total required

    k_wxs<<<256, 256, 0, stream>>>(Wx, Ws, bx, bs, Wxs, blog);
    k_ln<<<32768, 256, 0, stream>>>(fx, ln_g, ln_b, fx_norm);
    k_gemm_mid<<<dim3(2048, 2), 256, 0, stream>>>(fx_norm, Wxs, Wfx, blog, bfx, temp,
                                                  slice_w, fx_mid);
    k_zero<<<132, 256, 0, stream>>>(tok_acc, 33792);
    k_reduce<<<dim3(16, 32), 256, 0, stream>>>(slice_w, fx_mid, tok_acc, nrm_acc);
    k_tokens<<<32, 256, 0, stream>>>(tok_acc, nrm_acc, Wq, Wk, Wv, tlng, tlnb,
                                     W1, b1, W2, b2, Wo, tokWo);
    k_gemm_out<<<2048, 256, 0, stream>>>(slice_w, tokWo, bo, fx_norm, out);
}

// Round 6
// 685.912 us; speedup vs baseline: 1.5600x; 1.5600x over previous
//
#include <hip/hip_runtime.h>
#include <hip/hip_bf16.h>
#include <math.h>

static const int kN = 32768;   // tokens per batch

typedef __attribute__((ext_vector_type(8))) short short8;   // 8 bf16 = 4 VGPR (guide §3)
typedef __attribute__((ext_vector_type(4))) float f32x4;

__device__ inline unsigned short f2bf(float x) {
    union { float f; unsigned u; } v; v.f = x;
    unsigned r = v.u + 0x7FFF + ((v.u >> 16) & 1);   // round-to-nearest-even
    return (unsigned short)(r >> 16);
}

// ---------------------------------------------------------------------------
// K_zero: zero split-K accumulators (ws is poisoned 0xAA before every launch).
// ---------------------------------------------------------------------------
__global__ void k_zero(float* __restrict__ p, int n)
{
    int i = blockIdx.x * 256 + threadIdx.x;
    if (i < n) p[i] = 0.f;
}

// ---------------------------------------------------------------------------
// K_prep: WxsT_bf[n][k] = bf16(sum_d Wx[k][h*32+d]*Ws[d][g])  (n = h*32+g)
//         WfxT_bf[n][k] = bf16(Wfx[k][n]);  blog[n] = bx@Ws + bs
// Weights transposed to [N][K] so GEMM B-fragments are contiguous in K.
// ---------------------------------------------------------------------------
__global__ void k_prep(const float* __restrict__ Wx, const float* __restrict__ Ws,
                       const float* __restrict__ bx, const float* __restrict__ bs,
                       const float* __restrict__ Wfx,
                       unsigned short* __restrict__ WxsT, unsigned short* __restrict__ WfxT,
                       float* __restrict__ blog)
{
    __shared__ float ws_s[1024];           // Ws [32][32]
    int tid = threadIdx.x;
    for (int i = tid; i < 1024; i += 256) ws_s[i] = Ws[i];
    __syncthreads();
    int c = blockIdx.x;                    // K index 0..255
    int h = tid >> 5, g = tid & 31;
    const float* wrow = &Wx[c * 256 + h * 32];
    float s = 0.f;
    #pragma unroll
    for (int d = 0; d < 32; d++) s += wrow[d] * ws_s[d * 32 + g];
    WxsT[tid * 256 + c] = f2bf(s);
    WfxT[tid * 256 + c] = f2bf(Wfx[c * 256 + tid]);
    if (c == 0) {
        float t = 0.f;
        #pragma unroll
        for (int d = 0; d < 32; d++) t += bx[h * 32 + d] * ws_s[d * 32 + g];
        blog[tid] = t + bs[g];
    }
}

// ---------------------------------------------------------------------------
// K1: LayerNorm over C=256. Writes fp32 (residual path) + bf16 (GEMM A).
// ---------------------------------------------------------------------------
__global__ __launch_bounds__(256) void k_ln(const float* __restrict__ fx,
                                            const float* __restrict__ gam,
                                            const float* __restrict__ bet,
                                            float* __restrict__ out,
                                            unsigned short* __restrict__ outb)
{
    int lane = threadIdx.x & 63;
    long row = (long)blockIdx.x * 4 + (threadIdx.x >> 6);
    float4 v = *(const float4*)&fx[row * 256 + lane * 4];
    float s  = v.x + v.y + v.z + v.w;
    float ss = v.x * v.x + v.y * v.y + v.z * v.z + v.w * v.w;
    for (int off = 32; off; off >>= 1) { s += __shfl_down(s, off); ss += __shfl_down(ss, off); }
    s = __shfl(s, 0); ss = __shfl(ss, 0);
    float mu = s * (1.f / 256.f);
    float rstd = rsqrtf(ss * (1.f / 256.f) - mu * mu + 1e-5f);
    float4 gv = *(const float4*)&gam[lane * 4];
    float4 bv = *(const float4*)&bet[lane * 4];
    float4 o;
    o.x = (v.x - mu) * rstd * gv.x + bv.x;
    o.y = (v.y - mu) * rstd * gv.y + bv.y;
    o.z = (v.z - mu) * rstd * gv.z + bv.z;
    o.w = (v.w - mu) * rstd * gv.w + bv.w;
    *(float4*)&out[row * 256 + lane * 4] = o;
    ushort4 ob;
    ob.x = f2bf(o.x); ob.y = f2bf(o.y); ob.z = f2bf(o.z); ob.w = f2bf(o.w);
    *(ushort4*)&outb[row * 256 + lane * 4] = ob;
}

// ---------------------------------------------------------------------------
// K2: MFMA GEMM [BN,256]x[256,256] bf16. Tile M=64, N=256 (full), BK=32.
// 4 waves; wave w owns cols [w*64, w*64+64): 4x4 frags of 16x16x32.
// mode 0: +blog, /temp, per-head softmax -> slice_w_bf
// mode 1: +bfx                           -> fx_mid_bf
// ---------------------------------------------------------------------------
__global__ __launch_bounds__(256) void k_gemm_mid_mfma(
    const unsigned short* __restrict__ Abf,
    const unsigned short* __restrict__ WxsT, const unsigned short* __restrict__ WfxT,
    const float* __restrict__ blog, const float* __restrict__ bfx,
    const float* __restrict__ temp,
    unsigned short* __restrict__ swb, unsigned short* __restrict__ fmb)
{
    const int mode = blockIdx.y;
    const unsigned short* __restrict__ WT = mode ? WfxT : WxsT;
    const int tid = threadIdx.x;
    const int w = tid >> 6, l = tid & 63;
    const int r16 = l & 15, g4 = l >> 4;
    const long row0 = (long)blockIdx.x * 64;

    __shared__ unsigned short sA[64][40];    // [row][k], pad 40 (80B = 16B-aligned rows)
    __shared__ unsigned short sB[256][40];   // [col][k] (weights pre-transposed)

    f32x4 acc[4][4];
    #pragma unroll
    for (int mf = 0; mf < 4; mf++)
        #pragma unroll
        for (int nf = 0; nf < 4; nf++) acc[mf][nf] = (f32x4){0.f, 0.f, 0.f, 0.f};

    const int arow = tid >> 2, apart = tid & 3;
    for (int k0 = 0; k0 < 256; k0 += 32) {
        *(uint4*)&sA[arow][apart * 8] =
            *(const uint4*)&Abf[(row0 + arow) * 256 + k0 + apart * 8];
        #pragma unroll
        for (int p = 0; p < 4; p++) {
            int col = p * 64 + arow;
            *(uint4*)&sB[col][apart * 8] = *(const uint4*)&WT[col * 256 + k0 + apart * 8];
        }
        __syncthreads();
        short8 af[4], bfr[4];
        #pragma unroll
        for (int mf = 0; mf < 4; mf++) af[mf] = *(const short8*)&sA[mf * 16 + r16][g4 * 8];
        #pragma unroll
        for (int nf = 0; nf < 4; nf++) bfr[nf] = *(const short8*)&sB[w * 64 + nf * 16 + r16][g4 * 8];
        #pragma unroll
        for (int mf = 0; mf < 4; mf++)
            #pragma unroll
            for (int nf = 0; nf < 4; nf++)
                acc[mf][nf] = __builtin_amdgcn_mfma_f32_16x16x32_bf16(
                    af[mf], bfr[nf], acc[mf][nf], 0, 0, 0);
        __syncthreads();
    }

    if (mode == 0) {
        float rt0 = 1.0f / temp[w * 2], rt1 = 1.0f / temp[w * 2 + 1];
        float bl00 = blog[w * 64 + r16],      bl01 = blog[w * 64 + 16 + r16];
        float bl10 = blog[w * 64 + 32 + r16], bl11 = blog[w * 64 + 48 + r16];
        #pragma unroll
        for (int mf = 0; mf < 4; mf++) {
            #pragma unroll
            for (int ri = 0; ri < 4; ri++) {
                long row = row0 + mf * 16 + g4 * 4 + ri;
                // head j=0 (cols w*64 + [0,32))
                {
                    float z0 = (acc[mf][0][ri] + bl00) * rt0;
                    float z1 = (acc[mf][1][ri] + bl01) * rt0;
                    float m = fmaxf(z0, z1);
                    m = fmaxf(m, __shfl_xor(m, 1)); m = fmaxf(m, __shfl_xor(m, 2));
                    m = fmaxf(m, __shfl_xor(m, 4)); m = fmaxf(m, __shfl_xor(m, 8));
                    float e0 = __expf(z0 - m), e1 = __expf(z1 - m);
                    float sum = e0 + e1;
                    sum += __shfl_xor(sum, 1); sum += __shfl_xor(sum, 2);
                    sum += __shfl_xor(sum, 4); sum += __shfl_xor(sum, 8);
                    float inv = 1.0f / sum;
                    swb[row * 256 + w * 64 + r16]      = f2bf(e0 * inv);
                    swb[row * 256 + w * 64 + 16 + r16] = f2bf(e1 * inv);
                }
                // head j=1 (cols w*64 + [32,64))
                {
                    float z0 = (acc[mf][2][ri] + bl10) * rt1;
                    float z1 = (acc[mf][3][ri] + bl11) * rt1;
                    float m = fmaxf(z0, z1);
                    m = fmaxf(m, __shfl_xor(m, 1)); m = fmaxf(m, __shfl_xor(m, 2));
                    m = fmaxf(m, __shfl_xor(m, 4)); m = fmaxf(m, __shfl_xor(m, 8));
                    float e0 = __expf(z0 - m), e1 = __expf(z1 - m);
                    float sum = e0 + e1;
                    sum += __shfl_xor(sum, 1); sum += __shfl_xor(sum, 2);
                    sum += __shfl_xor(sum, 4); sum += __shfl_xor(sum, 8);
                    float inv = 1.0f / sum;
                    swb[row * 256 + w * 64 + 32 + r16] = f2bf(e0 * inv);
                    swb[row * 256 + w * 64 + 48 + r16] = f2bf(e1 * inv);
                }
            }
        }
    } else {
        float bb[4];
        #pragma unroll
        for (int nf = 0; nf < 4; nf++) bb[nf] = bfx[w * 64 + nf * 16 + r16];
        #pragma unroll
        for (int mf = 0; mf < 4; mf++)
            #pragma unroll
            for (int nf = 0; nf < 4; nf++)
                #pragma unroll
                for (int ri = 0; ri < 4; ri++) {
                    long row = row0 + mf * 16 + g4 * 4 + ri;
                    fmb[row * 256 + w * 64 + nf * 16 + r16] = f2bf(acc[mf][nf][ri] + bb[nf]);
                }
    }
}

// ---------------------------------------------------------------------------
// K3: slice_token/slice_norm reduction (bf16 inputs, fp32 accumulate).
// grid (16 chunks, 32 bh), 256 thr. Thread owns (g=tid/8, d0=(tid%8)*4).
// ---------------------------------------------------------------------------
__global__ __launch_bounds__(256) void k_reduce(
    const unsigned short* __restrict__ swb, const unsigned short* __restrict__ fmb,
    float* __restrict__ tok_acc, float* __restrict__ nrm_acc)
{
    const int bh = blockIdx.y;
    const int b = bh >> 3, h = bh & 7;
    const int tid = threadIdx.x;
    const int g = tid >> 3, dq = tid & 7, d0 = dq * 4;
    __shared__ float sw_t[64][36];
    __shared__ float fm_t[64][36];
    float4 acc = make_float4(0.f, 0.f, 0.f, 0.f);
    float nacc = 0.f;
    long base = (long)b * kN + (long)blockIdx.x * 2048;
    const int r = tid >> 2, q = tid & 3;

    for (int t0 = 0; t0 < 2048; t0 += 64) {
        long ga = (base + t0 + r) * 256 + h * 32 + q * 8;
        uint4 wv = *(const uint4*)&swb[ga];
        uint4 fv = *(const uint4*)&fmb[ga];
        __syncthreads();
        const unsigned* wu = (const unsigned*)&wv;
        const unsigned* fu = (const unsigned*)&fv;
        #pragma unroll
        for (int e = 0; e < 4; e++) {
            union { unsigned u; float f; } lo, hi;
            lo.u = wu[e] << 16; hi.u = wu[e] & 0xFFFF0000u;
            sw_t[r][q * 8 + 2 * e] = lo.f; sw_t[r][q * 8 + 2 * e + 1] = hi.f;
            lo.u = fu[e] << 16; hi.u = fu[e] & 0xFFFF0000u;
            fm_t[r][q * 8 + 2 * e] = lo.f; fm_t[r][q * 8 + 2 * e + 1] = hi.f;
        }
        __syncthreads();
        #pragma unroll 4
        for (int rr = 0; rr < 64; rr++) {
            float wgt = sw_t[rr][g];
            float4 f = *(const float4*)&fm_t[rr][d0];
            acc.x += wgt * f.x; acc.y += wgt * f.y; acc.z += wgt * f.z; acc.w += wgt * f.w;
            if (dq == 0) nacc += wgt;
        }
    }
    float* ta = &tok_acc[(bh * 32 + g) * 32 + d0];
    atomicAdd(&ta[0], acc.x); atomicAdd(&ta[1], acc.y);
    atomicAdd(&ta[2], acc.z); atomicAdd(&ta[3], acc.w);
    if (dq == 0) atomicAdd(&nrm_acc[bh * 32 + g], nacc);
}

// ---------------------------------------------------------------------------
// K4: per-(b,h) token block; writes tokWoT bf16 TRANSPOSED [b][c][hg].
// ---------------------------------------------------------------------------
__global__ __launch_bounds__(256) void k_tokens(
    const float* __restrict__ tok_acc, const float* __restrict__ nrm_acc,
    const float* __restrict__ Wq, const float* __restrict__ Wk, const float* __restrict__ Wv,
    const float* __restrict__ tlng, const float* __restrict__ tlnb,
    const float* __restrict__ W1, const float* __restrict__ b1,
    const float* __restrict__ W2, const float* __restrict__ b2,
    const float* __restrict__ Wo, unsigned short* __restrict__ tokWoT)
{
    const int bh = blockIdx.x, b = bh >> 3, h = bh & 7;
    const int tid = threadIdx.x;
    const int g = tid >> 3, dq = tid & 7, d0 = dq * 4;
    __shared__ float t[32][32], qm[32][32], km[32][32], vm[32][32];
    __shared__ float att[32][33], ot[32][32], hn[32][32], tk[32][32];
    __shared__ float h1[32][128];
    __shared__ float mu_s[32], rs_s[32];

    {
        float inv = 1.0f / (nrm_acc[bh * 32 + g] + 1e-5f);
        #pragma unroll
        for (int u = 0; u < 4; u++)
            t[g][d0 + u] = tok_acc[(bh * 32 + g) * 32 + d0 + u] * inv;
    }
    __syncthreads();
    #pragma unroll
    for (int u = 0; u < 4; u++) {
        int d = d0 + u;
        float sq = 0.f, sk = 0.f, sv = 0.f;
        for (int dd = 0; dd < 32; dd++) {
            float tv = t[g][dd];
            sq = fmaf(tv, Wq[dd * 32 + d], sq);
            sk = fmaf(tv, Wk[dd * 32 + d], sk);
            sv = fmaf(tv, Wv[dd * 32 + d], sv);
        }
        qm[g][d] = sq; km[g][d] = sk; vm[g][d] = sv;
    }
    __syncthreads();
    const float SC = 0.17677669529663687f;
    #pragma unroll
    for (int u = 0; u < 4; u++) {
        int gk = d0 + u;
        float s = 0.f;
        for (int dd = 0; dd < 32; dd++) s = fmaf(qm[g][dd], km[gk][dd], s);
        att[g][gk] = s * SC;
    }
    __syncthreads();
    if (tid < 32) {
        float m = -1e30f;
        for (int j = 0; j < 32; j++) m = fmaxf(m, att[tid][j]);
        float s = 0.f;
        for (int j = 0; j < 32; j++) { float e = expf(att[tid][j] - m); att[tid][j] = e; s += e; }
        float inv = 1.0f / s;
        for (int j = 0; j < 32; j++) att[tid][j] *= inv;
    }
    __syncthreads();
    #pragma unroll
    for (int u = 0; u < 4; u++) {
        int d = d0 + u;
        float s = 0.f;
        for (int kk = 0; kk < 32; kk++) s = fmaf(att[g][kk], vm[kk][d], s);
        ot[g][d] = s + t[g][d];
    }
    __syncthreads();
    if (tid < 32) {
        float s = 0.f, ss = 0.f;
        for (int dd = 0; dd < 32; dd++) { float v = ot[tid][dd]; s += v; ss += v * v; }
        float mu = s * (1.f / 32.f);
        mu_s[tid] = mu;
        rs_s[tid] = rsqrtf(ss * (1.f / 32.f) - mu * mu + 1e-5f);
    }
    __syncthreads();
    #pragma unroll
    for (int u = 0; u < 4; u++) {
        int d = d0 + u;
        hn[g][d] = (ot[g][d] - mu_s[g]) * rs_s[g] * tlng[d] + tlnb[d];
    }
    __syncthreads();
    for (int c = dq * 16; c < dq * 16 + 16; c++) {
        float s = b1[c];
        for (int dd = 0; dd < 32; dd++) s = fmaf(hn[g][dd], W1[dd * 128 + c], s);
        h1[g][c] = 0.5f * s * (1.0f + erff(s * 0.70710678118654752f));
    }
    __syncthreads();
    #pragma unroll
    for (int u = 0; u < 4; u++) {
        int d = d0 + u;
        float s = b2[d];
        for (int c = 0; c < 128; c++) s = fmaf(h1[g][c], W2[c * 32 + d], s);
        tk[g][d] = s + ot[g][d];
    }
    __syncthreads();
    {
        int c0 = dq * 32;
        for (int c = c0; c < c0 + 32; c++) {
            float s = 0.f;
            for (int dd = 0; dd < 32; dd++) s = fmaf(tk[g][dd], Wo[(h * 32 + dd) * 256 + c], s);
            tokWoT[(size_t)b * 65536 + c * 256 + h * 32 + g] = f2bf(s);
        }
    }
}

// ---------------------------------------------------------------------------
// K5: MFMA GEMM out = slice_w_bf @ tokWoT[b] + bo + fx_norm. Same tiling as K2.
// ---------------------------------------------------------------------------
__global__ __launch_bounds__(256) void k_gemm_out_mfma(
    const unsigned short* __restrict__ Abf,       // slice_w bf16 [BN][256]
    const unsigned short* __restrict__ tokWoT,    // [b][n=256][k=256] bf16
    const float* __restrict__ bo, const float* __restrict__ fx_norm,
    float* __restrict__ out)
{
    const int tid = threadIdx.x;
    const int w = tid >> 6, l = tid & 63;
    const int r16 = l & 15, g4 = l >> 4;
    const long row0 = (long)blockIdx.x * 64;
    const int b = (int)(row0 >> 15);
    const unsigned short* __restrict__ WT = tokWoT + (size_t)b * 65536;

    __shared__ unsigned short sA[64][40];
    __shared__ unsigned short sB[256][40];

    f32x4 acc[4][4];
    #pragma unroll
    for (int mf = 0; mf < 4; mf++)
        #pragma unroll
        for (int nf = 0; nf < 4; nf++) acc[mf][nf] = (f32x4){0.f, 0.f, 0.f, 0.f};

    const int arow = tid >> 2, apart = tid & 3;
    for (int k0 = 0; k0 < 256; k0 += 32) {
        *(uint4*)&sA[arow][apart * 8] =
            *(const uint4*)&Abf[(row0 + arow) * 256 + k0 + apart * 8];
        #pragma unroll
        for (int p = 0; p < 4; p++) {
            int col = p * 64 + arow;
            *(uint4*)&sB[col][apart * 8] = *(const uint4*)&WT[col * 256 + k0 + apart * 8];
        }
        __syncthreads();
        short8 af[4], bfr[4];
        #pragma unroll
        for (int mf = 0; mf < 4; mf++) af[mf] = *(const short8*)&sA[mf * 16 + r16][g4 * 8];
        #pragma unroll
        for (int nf = 0; nf < 4; nf++) bfr[nf] = *(const short8*)&sB[w * 64 + nf * 16 + r16][g4 * 8];
        #pragma unroll
        for (int mf = 0; mf < 4; mf++)
            #pragma unroll
            for (int nf = 0; nf < 4; nf++)
                acc[mf][nf] = __builtin_amdgcn_mfma_f32_16x16x32_bf16(
                    af[mf], bfr[nf], acc[mf][nf], 0, 0, 0);
        __syncthreads();
    }

    float bb[4];
    #pragma unroll
    for (int nf = 0; nf < 4; nf++) bb[nf] = bo[w * 64 + nf * 16 + r16];
    #pragma unroll
    for (int mf = 0; mf < 4; mf++)
        #pragma unroll
        for (int nf = 0; nf < 4; nf++)
            #pragma unroll
            for (int ri = 0; ri < 4; ri++) {
                long row = row0 + mf * 16 + g4 * 4 + ri;
                int col = w * 64 + nf * 16 + r16;
                out[row * 256 + col] = acc[mf][nf][ri] + bb[nf] + fx_norm[row * 256 + col];
            }
}

// ---------------------------------------------------------------------------
extern "C" void kernel_launch(void* const* d_in, const int* in_sizes, int n_in,
                              void* d_out, int out_size, void* d_ws, size_t ws_size,
                              hipStream_t stream)
{
    const float* fx   = (const float*)d_in[0];
    const float* ln_g = (const float*)d_in[1];
    const float* ln_b = (const float*)d_in[2];
    const float* Wx   = (const float*)d_in[3];
    const float* bx   = (const float*)d_in[4];
    const float* Wfx  = (const float*)d_in[5];
    const float* bfx  = (const float*)d_in[6];
    const float* Ws   = (const float*)d_in[7];
    const float* bs   = (const float*)d_in[8];
    const float* temp = (const float*)d_in[9];
    const float* Wq   = (const float*)d_in[10];
    const float* Wk   = (const float*)d_in[11];
    const float* Wv   = (const float*)d_in[12];
    const float* tlng = (const float*)d_in[13];
    const float* tlnb = (const float*)d_in[14];
    const float* W1   = (const float*)d_in[15];
    const float* b1   = (const float*)d_in[16];
    const float* W2   = (const float*)d_in[17];
    const float* b2   = (const float*)d_in[18];
    const float* Wo   = (const float*)d_in[19];
    const float* bo   = (const float*)d_in[20];
    float* out = (float*)d_out;

    char* ws = (char*)d_ws;
    float*          fx_norm = (float*)(ws + 0);                  // 134217728
    unsigned short* fxn_bf  = (unsigned short*)(ws + 134217728); //  67108864
    unsigned short* swb     = (unsigned short*)(ws + 201326592); //  67108864
    unsigned short* fmb     = (unsigned short*)(ws + 268435456); //  67108864
    unsigned short* WxsT    = (unsigned short*)(ws + 335544320); //    131072
    unsigned short* WfxT    = (unsigned short*)(ws + 335675392); //    131072
    float*          blog    = (float*)(ws + 335806464);          //      1024
    float*          tok_acc = (float*)(ws + 335807488);          //    131072
    float*          nrm_acc = (float*)(ws + 335938560);          //      4096
    unsigned short* tokWoT  = (unsigned short*)(ws + 335942656); //    524288
    if (ws_size < 336466944ULL) return;

    k_prep<<<256, 256, 0, stream>>>(Wx, Ws, bx, bs, Wfx, WxsT, WfxT, blog);
    k_ln<<<32768, 256, 0, stream>>>(fx, ln_g, ln_b, fx_norm, fxn_bf);
    k_gemm_mid_mfma<<<dim3(2048, 2), 256, 0, stream>>>(fxn_bf, WxsT, WfxT, blog, bfx, temp,
                                                       swb, fmb);
    k_zero<<<132, 256, 0, stream>>>(tok_acc, 33792);
    k_reduce<<<dim3(16, 32), 256, 0, stream>>>(swb, fmb, tok_acc, nrm_acc);
    k_tokens<<<32, 256, 0, stream>>>(tok_acc, nrm_acc, Wq, Wk, Wv, tlng, tlnb,
                                     W1, b1, W2, b2, Wo, tokWoT);
    k_gemm_out_mfma<<<2048, 256, 0, stream>>>(swb, tokWoT, bo, fx_norm, out);
}